// Round 1
// baseline (400.023 us; speedup 1.0000x reference)
//
#include <hip/hip_runtime.h>
#include <hip/hip_bf16.h>
#include <math.h>

// ALALLaDA router blend, factored form:
//   Act[t, k*512+f] = gelu(h[t,:]·W1[k,:,f] + b1[k,f])              (GEMM1, bf16)
//   G[a, kf]        = w[a,k] * sum_{t in win(a), um[t]} Act[t, kf]  (window kernel)
//   num[a,d]        = G[a,:]·W2s[:,d]  (+ cnt*sum_k w b2 in final)  (GEMM2, bf16)
//   out = h + 0.08 * LN(num/cnt) at masked positions with >=1 valid neighbor
// Shapes fixed: B=2, S=2048, D=2048, K=8, Fh=512, KF=4096, NT=4096.

#define ALPHA 0.08f
#define EPS 1e-5f

typedef __attribute__((ext_vector_type(8))) __bf16 bf16x8;
typedef __attribute__((ext_vector_type(8))) short short8;
typedef __attribute__((ext_vector_type(4))) float f32x4;

__device__ __forceinline__ unsigned short f2bf(float f) {
  unsigned u = __float_as_uint(f);
  u += 0x7fffu + ((u >> 16) & 1u);
  return (unsigned short)(u >> 16);
}
__device__ __forceinline__ float bf2f(unsigned short b) {
  return __uint_as_float(((unsigned)b) << 16);
}

#define GLD16(gptr, lptr)                                                     \
  __builtin_amdgcn_global_load_lds(                                           \
      (const __attribute__((address_space(1))) void*)(gptr),                  \
      (__attribute__((address_space(3))) void*)(lptr), 16, 0, 0)

// ---------------- pack h (f32 -> bf16) ----------------
__global__ void pack_h_kernel(const float* __restrict__ h,
                              unsigned short* __restrict__ hb) {
  const size_t i = ((size_t)blockIdx.x * 256 + threadIdx.x) * 8;
  const float4 x0 = *(const float4*)(h + i);
  const float4 x1 = *(const float4*)(h + i + 4);
  short8 o;
  o[0] = (short)f2bf(x0.x); o[1] = (short)f2bf(x0.y);
  o[2] = (short)f2bf(x0.z); o[3] = (short)f2bf(x0.w);
  o[4] = (short)f2bf(x1.x); o[5] = (short)f2bf(x1.y);
  o[6] = (short)f2bf(x1.z); o[7] = (short)f2bf(x1.w);
  *(short8*)(hb + i) = o;
}

// ---------------- transpose-pack weights (f32 [R][C] -> bf16 dst[c*stride + r]) ----------------
__global__ void transpose_pack_kernel(const float* __restrict__ src,
                                      unsigned short* __restrict__ dst,
                                      int R, int C, size_t dstStride,
                                      size_t dstExpStride) {
  __shared__ float tile[32][33];
  const int k = blockIdx.z;
  src += (size_t)k * (size_t)R * (size_t)C;
  dst += (size_t)k * dstExpStride;
  const int c0 = blockIdx.x * 32;
  const int r0 = blockIdx.y * 32;
  const int tx = threadIdx.x;  // 0..31
  const int ty = threadIdx.y;  // 0..7
#pragma unroll
  for (int i = 0; i < 4; ++i)
    tile[ty + 8 * i][tx] = src[(size_t)(r0 + ty + 8 * i) * C + (c0 + tx)];
  __syncthreads();
#pragma unroll
  for (int i = 0; i < 4; ++i) {
    const int c = c0 + ty + 8 * i;
    dst[(size_t)c * dstStride + (size_t)(r0 + tx)] = f2bf(tile[tx][ty + 8 * i]);
  }
}

// ---------------- router softmax (fp32 exact) ----------------
__global__ void router_kernel(const float* __restrict__ h,
                              const float* __restrict__ Wr,
                              const float* __restrict__ br,
                              float* __restrict__ w) {
  const int a = blockIdx.x;
  const int tid = threadIdx.x;
  const int lane = tid & 63, wid = tid >> 6;
  const size_t base = (size_t)a * 2048;
  const int d0 = tid * 8;
  float hv[8];
  *(float4*)(hv) = *(const float4*)(h + base + d0);
  *(float4*)(hv + 4) = *(const float4*)(h + base + d0 + 4);
  float acc[8];
#pragma unroll
  for (int k = 0; k < 8; ++k) {
    float wv[8];
    *(float4*)(wv) = *(const float4*)(Wr + (size_t)k * 2048 + d0);
    *(float4*)(wv + 4) = *(const float4*)(Wr + (size_t)k * 2048 + d0 + 4);
    float s = 0.f;
#pragma unroll
    for (int j = 0; j < 8; ++j) s += hv[j] * wv[j];
    acc[k] = s;
  }
#pragma unroll
  for (int off = 32; off > 0; off >>= 1)
#pragma unroll
    for (int k = 0; k < 8; ++k) acc[k] += __shfl_down(acc[k], off);
  __shared__ float red[4][8];
  __shared__ float logits[8];
  if (lane == 0)
#pragma unroll
    for (int k = 0; k < 8; ++k) red[wid][k] = acc[k];
  __syncthreads();
  if (tid < 8)
    logits[tid] = red[0][tid] + red[1][tid] + red[2][tid] + red[3][tid] + br[tid];
  __syncthreads();
  if (tid == 0) {
    float mx = logits[0];
#pragma unroll
    for (int k = 1; k < 8; ++k) mx = fmaxf(mx, logits[k]);
    float e[8], se = 0.f;
#pragma unroll
    for (int k = 0; k < 8; ++k) {
      e[k] = expf(logits[k] - mx);
      se += e[k];
    }
    const float is = 1.f / se;
#pragma unroll
    for (int k = 0; k < 8; ++k) w[(size_t)a * 8 + k] = e[k] * is;
  }
}

// ---------------- GEMM C = A * Bt^T (A [M][Kd], Bt [N][Kd], both bf16 row-major) ----------------
// m97-style: 128x128 tile, BK=32, 4 waves (2x2), 16x16x32 MFMA, global_load_lds width 16.
template <int EPI>  // 0: store f32 C. 1: +bias, exact GELU, store bf16.
__global__ __launch_bounds__(256, 2) void gemm_bt_kernel(
    const unsigned short* __restrict__ A, const unsigned short* __restrict__ Bt,
    float* __restrict__ Cf, unsigned short* __restrict__ Cb,
    const float* __restrict__ bias, int M, int N, int Kd) {
  __shared__ __align__(16) unsigned short As[4096];  // [128 rows][32 k]
  __shared__ __align__(16) unsigned short Bs[4096];  // [128 cols][32 k]
  const int tid = threadIdx.x;
  const int lane = tid & 63;
  const int wid = tid >> 6;
  const int bm = blockIdx.y * 128;
  const int bn = blockIdx.x * 128;
  const int wr = wid >> 1;
  const int wc = wid & 1;

  f32x4 acc[4][4];
#pragma unroll
  for (int m = 0; m < 4; ++m)
#pragma unroll
    for (int n = 0; n < 4; ++n) acc[m][n] = (f32x4){0.f, 0.f, 0.f, 0.f};

  // staging: inst i covers tile rows [i*16, i*16+16), 1KB LDS each; wave w does i=w and i=w+4
  const int srow = wid * 16 + (lane >> 2);
  const int scol = (lane & 3) * 8;
  const unsigned short* gA0 = A + (size_t)(bm + srow) * Kd + scol;
  const unsigned short* gA1 = gA0 + (size_t)64 * Kd;
  const unsigned short* gB0 = Bt + (size_t)(bn + srow) * Kd + scol;
  const unsigned short* gB1 = gB0 + (size_t)64 * Kd;
  unsigned short* lA0 = As + wid * 512;
  unsigned short* lA1 = As + (wid + 4) * 512;
  unsigned short* lB0 = Bs + wid * 512;
  unsigned short* lB1 = Bs + (wid + 4) * 512;

  const int aoff = (wr * 64 + (lane & 15)) * 32 + (lane >> 4) * 8;
  const int boff = (wc * 64 + (lane & 15)) * 32 + (lane >> 4) * 8;

  for (int k0 = 0; k0 < Kd; k0 += 32) {
    __syncthreads();  // previous iter's frag reads done -> safe to overwrite LDS
    GLD16(gA0 + k0, lA0);
    GLD16(gA1 + k0, lA1);
    GLD16(gB0 + k0, lB0);
    GLD16(gB1 + k0, lB1);
    __syncthreads();  // implies vmcnt(0): staging visible
    bf16x8 af[4], bfr[4];
#pragma unroll
    for (int m = 0; m < 4; ++m)
      af[m] = __builtin_bit_cast(bf16x8, *(const short8*)(As + aoff + m * 512));
#pragma unroll
    for (int n = 0; n < 4; ++n)
      bfr[n] = __builtin_bit_cast(bf16x8, *(const short8*)(Bs + boff + n * 512));
#pragma unroll
    for (int m = 0; m < 4; ++m)
#pragma unroll
      for (int n = 0; n < 4; ++n)
        acc[m][n] = __builtin_amdgcn_mfma_f32_16x16x32_bf16(af[m], bfr[n],
                                                            acc[m][n], 0, 0, 0);
  }

  // C/D layout: col = lane&15, row = (lane>>4)*4 + i (m89/m91-verified)
  const int r0 = bm + wr * 64 + (lane >> 4) * 4;
  const int c0 = bn + wc * 64 + (lane & 15);
#pragma unroll
  for (int m = 0; m < 4; ++m) {
#pragma unroll
    for (int n = 0; n < 4; ++n) {
      const int col = c0 + n * 16;
#pragma unroll
      for (int i = 0; i < 4; ++i) {
        const int row = r0 + m * 16 + i;
        const size_t off = (size_t)row * N + col;
        float v = acc[m][n][i];
        if (EPI == 1) {
          v += bias[col];
          v = 0.5f * v * (1.0f + erff(v * 0.70710678118654752f));  // exact GELU
          Cb[off] = f2bf(v);
        } else {
          Cf[off] = v;
        }
      }
    }
  }
}

// ---------------- windowed neighbor sum + router weighting ----------------
__global__ void window_kernel(const unsigned short* __restrict__ Act,
                              const float* __restrict__ w,
                              const int* __restrict__ mask,
                              const int* __restrict__ rptr,
                              unsigned short* __restrict__ G) {
  const int a = blockIdx.y;
  const int s = a & 2047;
  const int tb = a & ~2047;
  const int c = blockIdx.x * 2048 + threadIdx.x * 8;
  const int r = rptr[0];
  float acc[8] = {0.f, 0.f, 0.f, 0.f, 0.f, 0.f, 0.f, 0.f};
  for (int o = -r; o <= r; ++o) {
    if (o == 0) continue;
    const int t = s + o;
    if ((unsigned)t < 2048u && mask[tb + t] == 0) {
      const short8 v = *(const short8*)(Act + (size_t)(tb + t) * 4096 + c);
#pragma unroll
      for (int j = 0; j < 8; ++j) acc[j] += bf2f((unsigned short)v[j]);
    }
  }
  const float wv = w[(size_t)a * 8 + (c >> 9)];
  short8 o8;
#pragma unroll
  for (int j = 0; j < 8; ++j) o8[j] = (short)f2bf(acc[j] * wv);
  *(short8*)(G + (size_t)a * 4096 + c) = o8;
}

// ---------------- final: bias-combine, mean, LN, blend ----------------
__global__ void final_kernel(const float* __restrict__ h,
                             const int* __restrict__ mask,
                             const float* __restrict__ w,
                             const float* __restrict__ b2,
                             const float* __restrict__ num,
                             const int* __restrict__ rptr,
                             float* __restrict__ out) {
  const int a = blockIdx.x;
  const int tid = threadIdx.x;
  const int lane = tid & 63, wid = tid >> 6;
  const int s = a & 2047;
  const int tb = a & ~2047;
  const size_t base = (size_t)a * 2048;
  const int d0 = tid * 8;
  const int r = rptr[0];
  int cnt = 0;
  for (int o = -r; o <= r; ++o) {
    if (o == 0) continue;
    const int t = s + o;
    if ((unsigned)t < 2048u && mask[tb + t] == 0) ++cnt;
  }
  const bool active = (mask[a] != 0) && (cnt > 0);
  if (!active) {  // block-uniform branch: exact fp32 pass-through
    const float4 x0 = *(const float4*)(h + base + d0);
    const float4 x1 = *(const float4*)(h + base + d0 + 4);
    *(float4*)(out + base + d0) = x0;
    *(float4*)(out + base + d0 + 4) = x1;
    return;
  }
  float wk[8];
#pragma unroll
  for (int k = 0; k < 8; ++k) wk[k] = w[(size_t)a * 8 + k];
  const float cntf = (float)cnt;
  const float icnt = 1.0f / cntf;
  float mval[8];
  float s1 = 0.f, s2 = 0.f;
#pragma unroll
  for (int j = 0; j < 8; ++j) {
    const int d = d0 + j;
    float wb2 = 0.f;
#pragma unroll
    for (int k = 0; k < 8; ++k) wb2 += wk[k] * b2[(size_t)k * 2048 + d];
    const float v = (num[base + d] + cntf * wb2) * icnt;
    mval[j] = v;
    s1 += v;
    s2 += v * v;
  }
#pragma unroll
  for (int off = 32; off > 0; off >>= 1) {
    s1 += __shfl_down(s1, off);
    s2 += __shfl_down(s2, off);
  }
  __shared__ float red[8];
  if (lane == 0) {
    red[wid] = s1;
    red[4 + wid] = s2;
  }
  __syncthreads();
  const float S1 = red[0] + red[1] + red[2] + red[3];
  const float S2 = red[4] + red[5] + red[6] + red[7];
  const float mu = S1 * (1.0f / 2048.0f);
  const float var = S2 * (1.0f / 2048.0f) - mu * mu;
  const float rin = rsqrtf(var + EPS);
#pragma unroll
  for (int j = 0; j < 8; ++j) {
    const int d = d0 + j;
    out[base + d] = h[base + d] + ALPHA * ((mval[j] - mu) * rin);
  }
}

// ---------------- launch ----------------
extern "C" void kernel_launch(void* const* d_in, const int* in_sizes, int n_in,
                              void* d_out, int out_size, void* d_ws,
                              size_t ws_size, hipStream_t stream) {
  const float* h = (const float*)d_in[0];
  const int* mask = (const int*)d_in[1];
  const float* Wr = (const float*)d_in[2];
  const float* br = (const float*)d_in[3];
  const float* W1 = (const float*)d_in[4];
  const float* b1 = (const float*)d_in[5];
  const float* W2 = (const float*)d_in[6];
  const float* b2 = (const float*)d_in[7];
  const int* rptr = (const int*)d_in[8];
  float* out = (float*)d_out;

  char* ws = (char*)d_ws;
  // layout (bytes):
  //   hb   [4096*2048] bf16 @ 0          (16 MiB)
  //   B1t  [4096*2048] bf16 @ 16777216   (16 MiB)   W1^T stacked: [kf][d]
  //   B2t  [2048*4096] bf16 @ 33554432   (16 MiB)   W2^T stacked: [d][kf]
  //   Act  [4096*4096] bf16 @ 50331648   (32 MiB)   (aliased by num f32 later)
  //   G    [4096*4096] bf16 @ 83886080   (32 MiB)
  //   w    [4096*8]    f32  @ 117440512  (128 KiB)
  unsigned short* hb = (unsigned short*)(ws + 0);
  unsigned short* B1t = (unsigned short*)(ws + 16777216);
  unsigned short* B2t = (unsigned short*)(ws + 33554432);
  unsigned short* Act = (unsigned short*)(ws + 50331648);
  unsigned short* G = (unsigned short*)(ws + 83886080);
  float* num = (float*)(ws + 50331648);  // alias Act (dead after window_kernel)
  float* wbuf = (float*)(ws + 117440512);

  pack_h_kernel<<<4096, 256, 0, stream>>>(h, hb);
  router_kernel<<<4096, 256, 0, stream>>>(h, Wr, br, wbuf);
  // W1 [k][d][f] -> B1t[(k*512+f)*2048 + d]
  transpose_pack_kernel<<<dim3(16, 64, 8), dim3(32, 8), 0, stream>>>(
      W1, B1t, 2048, 512, 2048, (size_t)512 * 2048);
  // W2 [k][f][d] -> B2t[d*4096 + k*512 + f]
  transpose_pack_kernel<<<dim3(64, 16, 8), dim3(32, 8), 0, stream>>>(
      W2, B2t, 512, 2048, 4096, 512);
  // GEMM1: Act = gelu(hb * B1t^T + b1)   [4096 x 4096], Kd=2048
  gemm_bt_kernel<1><<<dim3(32, 32), 256, 0, stream>>>(hb, B1t, nullptr, Act,
                                                      b1, 4096, 4096, 2048);
  // G = w * windowed-sum(Act)
  window_kernel<<<dim3(2, 4096), 256, 0, stream>>>(Act, wbuf, mask, rptr, G);
  // GEMM2: num = G * B2t^T   [4096 x 2048], Kd=4096
  gemm_bt_kernel<0><<<dim3(16, 32), 256, 0, stream>>>(G, B2t, num, nullptr,
                                                      nullptr, 4096, 2048, 4096);
  final_kernel<<<4096, 256, 0, stream>>>(h, mask, wbuf, b2, num, rptr, out);
}

// Round 2
// 375.460 us; speedup vs baseline: 1.0654x; 1.0654x over previous
//
#include <hip/hip_runtime.h>
#include <hip/hip_bf16.h>
#include <math.h>

// ALALLaDA router blend, factored + row-compacted form:
//   scan: unm_idx = positions with mask==0 (count Nu), order-preserving;
//         msk_idx = masked positions with >=1 valid neighbor (count Nm);
//         ru[t] = exclusive prefix count of unmasked positions.
//   Act_c[i, kf] = gelu(h[unm_idx[i],:]·W1 + b1)          (GEMM1, M=Nu)
//   G_c[i, kf]   = w[a]*sum_{j in [ru[lo],ru[hi+1])} Act_c[j]  (a=msk_idx[i])
//   num_c[i,:]   = G_c[i,:]·W2s                           (GEMM2, M=Nm)
//   out = h + 0.08*LN((num_c+cnt*w·b2)/cnt) at active masked positions.
// Shapes fixed: B=2, S=2048, D=2048, K=8, Fh=512, KF=4096, NT=4096.

#define ALPHA 0.08f
#define EPS 1e-5f

typedef __attribute__((ext_vector_type(8))) __bf16 bf16x8;
typedef __attribute__((ext_vector_type(8))) short short8;
typedef __attribute__((ext_vector_type(4))) float f32x4;

__device__ __forceinline__ unsigned short f2bf(float f) {
  unsigned u = __float_as_uint(f);
  u += 0x7fffu + ((u >> 16) & 1u);
  return (unsigned short)(u >> 16);
}
__device__ __forceinline__ float bf2f(unsigned short b) {
  return __uint_as_float(((unsigned)b) << 16);
}

#define GLD16(gptr, lptr)                                                     \
  __builtin_amdgcn_global_load_lds(                                           \
      (const __attribute__((address_space(1))) void*)(gptr),                  \
      (__attribute__((address_space(3))) void*)(lptr), 16, 0, 0)

__device__ __forceinline__ int wave_incl_scan(int v, int lane) {
#pragma unroll
  for (int off = 1; off < 64; off <<= 1) {
    int t = __shfl_up(v, off);
    if (lane >= off) v += t;
  }
  return v;
}

// ---------------- compaction scan (single block) ----------------
__global__ __launch_bounds__(1024) void scan_kernel(
    const int* __restrict__ mask, const int* __restrict__ rptr,
    int* __restrict__ ru, int* __restrict__ unm_idx,
    int* __restrict__ msk_idx, int* __restrict__ pos2row,
    int* __restrict__ counts) {
  __shared__ int sru[4097];
  __shared__ int wsum[16];
  __shared__ int wsum2[17];
  const int tid = threadIdx.x;
  const int lane = tid & 63, wv = tid >> 6;
  const int t0 = tid * 4;
  const int4 m4 = *(const int4*)(mask + t0);
  int f[4];
  f[0] = (m4.x == 0); f[1] = (m4.y == 0); f[2] = (m4.z == 0); f[3] = (m4.w == 0);
  const int tsum = f[0] + f[1] + f[2] + f[3];
  const int isc = wave_incl_scan(tsum, lane);
  if (lane == 63) wsum[wv] = isc;
  __syncthreads();
  if (tid == 0) {
    int acc = 0;
#pragma unroll
    for (int i = 0; i < 16; ++i) { int v = wsum[i]; wsum[i] = acc; acc += v; }
    sru[4096] = acc;
    counts[0] = acc;
    ru[4096] = acc;
  }
  __syncthreads();
  int ex = wsum[wv] + isc - tsum;
#pragma unroll
  for (int j = 0; j < 4; ++j) {
    sru[t0 + j] = ex;
    ru[t0 + j] = ex;
    if (f[j]) unm_idx[ex] = t0 + j;
    ex += f[j];
  }
  __syncthreads();
  // pass 2: masked positions with >=1 valid neighbor
  const int r = rptr[0];
  int mval[4] = {m4.x, m4.y, m4.z, m4.w};
  int g[4];
#pragma unroll
  for (int j = 0; j < 4; ++j) {
    const int t = t0 + j;
    const int s = t & 2047, tb = t & ~2047;
    const int lo = max(s - r, 0), hi = min(s + r, 2047);
    const int cnt = sru[tb + hi + 1] - sru[tb + lo];
    g[j] = (mval[j] != 0 && cnt > 0) ? 1 : 0;
  }
  const int tsum2 = g[0] + g[1] + g[2] + g[3];
  const int isc2 = wave_incl_scan(tsum2, lane);
  if (lane == 63) wsum2[wv] = isc2;
  __syncthreads();
  if (tid == 0) {
    int acc = 0;
#pragma unroll
    for (int i = 0; i < 16; ++i) { int v = wsum2[i]; wsum2[i] = acc; acc += v; }
    counts[1] = acc;
  }
  __syncthreads();
  int ex2 = wsum2[wv] + isc2 - tsum2;
#pragma unroll
  for (int j = 0; j < 4; ++j) {
    const int t = t0 + j;
    pos2row[t] = g[j] ? ex2 : -1;
    if (g[j]) msk_idx[ex2] = t;
    ex2 += g[j];
  }
}

// ---------------- pack/gather h rows (f32 -> bf16, compact unmasked) -------
__global__ void pack_h_kernel(const float* __restrict__ h,
                              const int* __restrict__ unm_idx,
                              const int* __restrict__ counts,
                              unsigned short* __restrict__ hbc) {
  const int i = blockIdx.x;
  if (i >= counts[0]) return;
  const int t = unm_idx[i];
  const int d0 = threadIdx.x * 8;
  const float4 x0 = *(const float4*)(h + (size_t)t * 2048 + d0);
  const float4 x1 = *(const float4*)(h + (size_t)t * 2048 + d0 + 4);
  short8 o;
  o[0] = (short)f2bf(x0.x); o[1] = (short)f2bf(x0.y);
  o[2] = (short)f2bf(x0.z); o[3] = (short)f2bf(x0.w);
  o[4] = (short)f2bf(x1.x); o[5] = (short)f2bf(x1.y);
  o[6] = (short)f2bf(x1.z); o[7] = (short)f2bf(x1.w);
  *(short8*)(hbc + (size_t)i * 2048 + d0) = o;
}

// ---------------- transpose-pack weights (f32 [R][C] -> bf16 dst[c*stride + r]) ----------------
__global__ void transpose_pack_kernel(const float* __restrict__ src,
                                      unsigned short* __restrict__ dst,
                                      int R, int C, size_t dstStride,
                                      size_t dstExpStride) {
  __shared__ float tile[32][33];
  const int k = blockIdx.z;
  src += (size_t)k * (size_t)R * (size_t)C;
  dst += (size_t)k * dstExpStride;
  const int c0 = blockIdx.x * 32;
  const int r0 = blockIdx.y * 32;
  const int tx = threadIdx.x;  // 0..31
  const int ty = threadIdx.y;  // 0..7
#pragma unroll
  for (int i = 0; i < 4; ++i)
    tile[ty + 8 * i][tx] = src[(size_t)(r0 + ty + 8 * i) * C + (c0 + tx)];
  __syncthreads();
#pragma unroll
  for (int i = 0; i < 4; ++i) {
    const int c = c0 + ty + 8 * i;
    dst[(size_t)c * dstStride + (size_t)(r0 + tx)] = f2bf(tile[tx][ty + 8 * i]);
  }
}

// ---------------- router softmax (fp32 exact) ----------------
__global__ void router_kernel(const float* __restrict__ h,
                              const float* __restrict__ Wr,
                              const float* __restrict__ br,
                              float* __restrict__ w) {
  const int a = blockIdx.x;
  const int tid = threadIdx.x;
  const int lane = tid & 63, wid = tid >> 6;
  const size_t base = (size_t)a * 2048;
  const int d0 = tid * 8;
  float hv[8];
  *(float4*)(hv) = *(const float4*)(h + base + d0);
  *(float4*)(hv + 4) = *(const float4*)(h + base + d0 + 4);
  float acc[8];
#pragma unroll
  for (int k = 0; k < 8; ++k) {
    float wvv[8];
    *(float4*)(wvv) = *(const float4*)(Wr + (size_t)k * 2048 + d0);
    *(float4*)(wvv + 4) = *(const float4*)(Wr + (size_t)k * 2048 + d0 + 4);
    float s = 0.f;
#pragma unroll
    for (int j = 0; j < 8; ++j) s += hv[j] * wvv[j];
    acc[k] = s;
  }
#pragma unroll
  for (int off = 32; off > 0; off >>= 1)
#pragma unroll
    for (int k = 0; k < 8; ++k) acc[k] += __shfl_down(acc[k], off);
  __shared__ float red[4][8];
  __shared__ float logits[8];
  if (lane == 0)
#pragma unroll
    for (int k = 0; k < 8; ++k) red[wid][k] = acc[k];
  __syncthreads();
  if (tid < 8)
    logits[tid] = red[0][tid] + red[1][tid] + red[2][tid] + red[3][tid] + br[tid];
  __syncthreads();
  if (tid == 0) {
    float mx = logits[0];
#pragma unroll
    for (int k = 1; k < 8; ++k) mx = fmaxf(mx, logits[k]);
    float e[8], se = 0.f;
#pragma unroll
    for (int k = 0; k < 8; ++k) {
      e[k] = expf(logits[k] - mx);
      se += e[k];
    }
    const float is = 1.f / se;
#pragma unroll
    for (int k = 0; k < 8; ++k) w[(size_t)a * 8 + k] = e[k] * is;
  }
}

// ---------------- GEMM C = A * Bt^T (A [M][Kd], Bt [N][Kd], both bf16 row-major) ----------------
// m97-style: 128x128 tile, BK=32, 4 waves (2x2), 16x16x32 MFMA, global_load_lds width 16.
// M limited at runtime by counts[cidx]; blocks fully past the limit exit.
template <int EPI>  // 0: store f32 C. 1: +bias, exact GELU, store bf16.
__global__ __launch_bounds__(256, 2) void gemm_bt_kernel(
    const unsigned short* __restrict__ A, const unsigned short* __restrict__ Bt,
    float* __restrict__ Cf, unsigned short* __restrict__ Cb,
    const float* __restrict__ bias, const int* __restrict__ counts, int cidx,
    int N, int Kd) {
  const int Mlim = counts[cidx];
  const int bm = blockIdx.y * 128;
  if (bm >= Mlim) return;
  __shared__ __align__(16) unsigned short As[4096];  // [128 rows][32 k]
  __shared__ __align__(16) unsigned short Bs[4096];  // [128 cols][32 k]
  const int tid = threadIdx.x;
  const int lane = tid & 63;
  const int wid = tid >> 6;
  const int bn = blockIdx.x * 128;
  const int wr = wid >> 1;
  const int wc = wid & 1;

  f32x4 acc[4][4];
#pragma unroll
  for (int m = 0; m < 4; ++m)
#pragma unroll
    for (int n = 0; n < 4; ++n) acc[m][n] = (f32x4){0.f, 0.f, 0.f, 0.f};

  const int srow = wid * 16 + (lane >> 2);
  const int scol = (lane & 3) * 8;
  const unsigned short* gA0 = A + (size_t)(bm + srow) * Kd + scol;
  const unsigned short* gA1 = gA0 + (size_t)64 * Kd;
  const unsigned short* gB0 = Bt + (size_t)(bn + srow) * Kd + scol;
  const unsigned short* gB1 = gB0 + (size_t)64 * Kd;
  unsigned short* lA0 = As + wid * 512;
  unsigned short* lA1 = As + (wid + 4) * 512;
  unsigned short* lB0 = Bs + wid * 512;
  unsigned short* lB1 = Bs + (wid + 4) * 512;

  const int aoff = (wr * 64 + (lane & 15)) * 32 + (lane >> 4) * 8;
  const int boff = (wc * 64 + (lane & 15)) * 32 + (lane >> 4) * 8;

  for (int k0 = 0; k0 < Kd; k0 += 32) {
    __syncthreads();
    GLD16(gA0 + k0, lA0);
    GLD16(gA1 + k0, lA1);
    GLD16(gB0 + k0, lB0);
    GLD16(gB1 + k0, lB1);
    __syncthreads();
    bf16x8 af[4], bfr[4];
#pragma unroll
    for (int m = 0; m < 4; ++m)
      af[m] = __builtin_bit_cast(bf16x8, *(const short8*)(As + aoff + m * 512));
#pragma unroll
    for (int n = 0; n < 4; ++n)
      bfr[n] = __builtin_bit_cast(bf16x8, *(const short8*)(Bs + boff + n * 512));
#pragma unroll
    for (int m = 0; m < 4; ++m)
#pragma unroll
      for (int n = 0; n < 4; ++n)
        acc[m][n] = __builtin_amdgcn_mfma_f32_16x16x32_bf16(af[m], bfr[n],
                                                            acc[m][n], 0, 0, 0);
  }

  // C/D layout: col = lane&15, row = (lane>>4)*4 + i (m89/m91-verified)
  const int r0 = bm + wr * 64 + (lane >> 4) * 4;
  const int c0 = bn + wc * 64 + (lane & 15);
#pragma unroll
  for (int m = 0; m < 4; ++m) {
#pragma unroll
    for (int n = 0; n < 4; ++n) {
      const int col = c0 + n * 16;
#pragma unroll
      for (int i = 0; i < 4; ++i) {
        const int row = r0 + m * 16 + i;
        if (row >= Mlim) continue;
        const size_t off = (size_t)row * N + col;
        float v = acc[m][n][i];
        if (EPI == 1) {
          v += bias[col];
          v = 0.5f * v * (1.0f + erff(v * 0.70710678118654752f));  // exact GELU
          Cb[off] = f2bf(v);
        } else {
          Cf[off] = v;
        }
      }
    }
  }
}

// ---------------- windowed neighbor sum + router weighting (compact) -------
__global__ void window_kernel(const unsigned short* __restrict__ Act_c,
                              const float* __restrict__ w,
                              const int* __restrict__ msk_idx,
                              const int* __restrict__ ru,
                              const int* __restrict__ rptr,
                              const int* __restrict__ counts,
                              unsigned short* __restrict__ G_c) {
  const int i = blockIdx.y;
  if (i >= counts[1]) return;
  const int a = msk_idx[i];
  const int s = a & 2047;
  const int tb = a & ~2047;
  const int r = rptr[0];
  const int lo = max(s - r, 0), hi = min(s + r, 2047);
  const int jlo = ru[tb + lo], jhi = ru[tb + hi + 1];
  const int c = blockIdx.x * 2048 + threadIdx.x * 8;
  float acc[8] = {0.f, 0.f, 0.f, 0.f, 0.f, 0.f, 0.f, 0.f};
  for (int j = jlo; j < jhi; ++j) {
    const short8 v = *(const short8*)(Act_c + (size_t)j * 4096 + c);
#pragma unroll
    for (int jj = 0; jj < 8; ++jj) acc[jj] += bf2f((unsigned short)v[jj]);
  }
  const float wv = w[(size_t)a * 8 + (c >> 9)];
  short8 o8;
#pragma unroll
  for (int jj = 0; jj < 8; ++jj) o8[jj] = (short)f2bf(acc[jj] * wv);
  *(short8*)(G_c + (size_t)i * 4096 + c) = o8;
}

// ---------------- final: bias-combine, mean, LN, blend ----------------
__global__ void final_kernel(const float* __restrict__ h,
                             const int* __restrict__ pos2row,
                             const float* __restrict__ w,
                             const float* __restrict__ b2,
                             const float* __restrict__ num_c,
                             const int* __restrict__ ru,
                             const int* __restrict__ rptr,
                             float* __restrict__ out) {
  const int a = blockIdx.x;
  const int tid = threadIdx.x;
  const int lane = tid & 63, wid = tid >> 6;
  const size_t base = (size_t)a * 2048;
  const int d0 = tid * 8;
  const int row = pos2row[a];
  if (row < 0) {  // block-uniform: exact fp32 pass-through
    const float4 x0 = *(const float4*)(h + base + d0);
    const float4 x1 = *(const float4*)(h + base + d0 + 4);
    *(float4*)(out + base + d0) = x0;
    *(float4*)(out + base + d0 + 4) = x1;
    return;
  }
  const int s = a & 2047;
  const int tb = a & ~2047;
  const int r = rptr[0];
  const int lo = max(s - r, 0), hi = min(s + r, 2047);
  const int cnt = ru[tb + hi + 1] - ru[tb + lo];
  float wk[8];
#pragma unroll
  for (int k = 0; k < 8; ++k) wk[k] = w[(size_t)a * 8 + k];
  const float cntf = (float)cnt;
  const float icnt = 1.0f / cntf;
  float mval[8];
  float s1 = 0.f, s2 = 0.f;
#pragma unroll
  for (int j = 0; j < 8; ++j) {
    const int d = d0 + j;
    float wb2 = 0.f;
#pragma unroll
    for (int k = 0; k < 8; ++k) wb2 += wk[k] * b2[(size_t)k * 2048 + d];
    const float v = (num_c[(size_t)row * 2048 + d] + cntf * wb2) * icnt;
    mval[j] = v;
    s1 += v;
    s2 += v * v;
  }
#pragma unroll
  for (int off = 32; off > 0; off >>= 1) {
    s1 += __shfl_down(s1, off);
    s2 += __shfl_down(s2, off);
  }
  __shared__ float red[8];
  if (lane == 0) {
    red[wid] = s1;
    red[4 + wid] = s2;
  }
  __syncthreads();
  const float S1 = red[0] + red[1] + red[2] + red[3];
  const float S2 = red[4] + red[5] + red[6] + red[7];
  const float mu = S1 * (1.0f / 2048.0f);
  const float var = S2 * (1.0f / 2048.0f) - mu * mu;
  const float rin = rsqrtf(var + EPS);
#pragma unroll
  for (int j = 0; j < 8; ++j) {
    const int d = d0 + j;
    out[base + d] = h[base + d] + ALPHA * ((mval[j] - mu) * rin);
  }
}

// ---------------- launch ----------------
extern "C" void kernel_launch(void* const* d_in, const int* in_sizes, int n_in,
                              void* d_out, int out_size, void* d_ws,
                              size_t ws_size, hipStream_t stream) {
  const float* h = (const float*)d_in[0];
  const int* mask = (const int*)d_in[1];
  const float* Wr = (const float*)d_in[2];
  const float* br = (const float*)d_in[3];
  const float* W1 = (const float*)d_in[4];
  const float* b1 = (const float*)d_in[5];
  const float* W2 = (const float*)d_in[6];
  const float* b2 = (const float*)d_in[7];
  const int* rptr = (const int*)d_in[8];
  float* out = (float*)d_out;

  char* ws = (char*)d_ws;
  // layout (bytes):
  //   hbc  [4096*2048] bf16 @ 0          (16 MiB)  compact unmasked h, bf16
  //   B1t  [4096*2048] bf16 @ 16777216   (16 MiB)  W1^T stacked: [kf][d]
  //   B2t  [2048*4096] bf16 @ 33554432   (16 MiB)  W2^T stacked: [d][kf]
  //   Act_c[4096*4096] bf16 @ 50331648   (32 MiB)  (aliased by num_c f32 later)
  //   G_c  [4096*4096] bf16 @ 83886080   (32 MiB)
  //   w    [4096*8]    f32  @ 117440512  (128 KiB)
  //   ints: ru[4097], unm_idx[4096], msk_idx[4096], pos2row[4096], counts[2]
  unsigned short* hbc = (unsigned short*)(ws + 0);
  unsigned short* B1t = (unsigned short*)(ws + 16777216);
  unsigned short* B2t = (unsigned short*)(ws + 33554432);
  unsigned short* Act_c = (unsigned short*)(ws + 50331648);
  unsigned short* G_c = (unsigned short*)(ws + 83886080);
  float* num_c = (float*)(ws + 50331648);  // alias Act_c (dead after window)
  float* wbuf = (float*)(ws + 117440512);
  int* ru = (int*)(ws + 117571584);
  int* unm_idx = ru + 4100;
  int* msk_idx = unm_idx + 4096;
  int* pos2row = msk_idx + 4096;
  int* counts = pos2row + 4096;

  scan_kernel<<<1, 1024, 0, stream>>>(mask, rptr, ru, unm_idx, msk_idx,
                                      pos2row, counts);
  pack_h_kernel<<<4096, 256, 0, stream>>>(h, unm_idx, counts, hbc);
  router_kernel<<<4096, 256, 0, stream>>>(h, Wr, br, wbuf);
  // W1 [k][d][f] -> B1t[(k*512+f)*2048 + d]
  transpose_pack_kernel<<<dim3(16, 64, 8), dim3(32, 8), 0, stream>>>(
      W1, B1t, 2048, 512, 2048, (size_t)512 * 2048);
  // W2 [k][f][d] -> B2t[d*4096 + k*512 + f]
  transpose_pack_kernel<<<dim3(64, 16, 8), dim3(32, 8), 0, stream>>>(
      W2, B2t, 512, 2048, 4096, 512);
  // GEMM1: Act_c = gelu(hbc * B1t^T + b1)   [Nu x 4096], Kd=2048
  gemm_bt_kernel<1><<<dim3(32, 32), 256, 0, stream>>>(
      hbc, B1t, nullptr, Act_c, b1, counts, 0, 4096, 2048);
  // G_c = w * windowed-sum(Act_c)   [Nm x 4096]
  window_kernel<<<dim3(2, 4096), 256, 0, stream>>>(Act_c, wbuf, msk_idx, ru,
                                                   rptr, counts, G_c);
  // GEMM2: num_c = G_c * B2t^T   [Nm x 2048], Kd=4096
  gemm_bt_kernel<0><<<dim3(16, 32), 256, 0, stream>>>(
      G_c, B2t, num_c, nullptr, nullptr, counts, 1, 2048, 4096);
  final_kernel<<<4096, 256, 0, stream>>>(h, pos2row, wbuf, b2, num_c, ru,
                                         rptr, out);
}

// Round 3
// 346.738 us; speedup vs baseline: 1.1537x; 1.0828x over previous
//
#include <hip/hip_runtime.h>
#include <hip/hip_bf16.h>
#include <math.h>

// ALALLaDA router blend, factored + row-compacted form:
//   scan: unm_idx = positions with mask==0 (count Nu), order-preserving;
//         msk_idx = masked positions with >=1 valid neighbor (count Nm);
//         ru[t] = exclusive prefix count of unmasked positions.
//   Act_c[i, kf] = gelu(h[unm_idx[i],:]·W1 + b1)          (GEMM1, M=Nu)
//   G_c[i, kf]   = w[a]*sum_{j in [ru[lo],ru[hi+1])} Act_c[j]  (a=msk_idx[i])
//   num_c[i,:]   = G_c[i,:]·W2s                           (GEMM2, M=Nm)
//   out = h + 0.08*LN((num_c+cnt*w·b2)/cnt) at active masked positions.
// GEMM: 128x128 tile, BK=32, 4-buffer depth-3 prefetch with counted vmcnt
// (T3/T4): one s_barrier per K-step, s_waitcnt vmcnt(8) steady-state.
// Shapes fixed: B=2, S=2048, D=2048, K=8, Fh=512, KF=4096, NT=4096.

#define ALPHA 0.08f
#define EPS 1e-5f

typedef __attribute__((ext_vector_type(8))) __bf16 bf16x8;
typedef __attribute__((ext_vector_type(8))) short short8;
typedef __attribute__((ext_vector_type(4))) float f32x4;

__device__ __forceinline__ unsigned short f2bf(float f) {
  unsigned u = __float_as_uint(f);
  u += 0x7fffu + ((u >> 16) & 1u);
  return (unsigned short)(u >> 16);
}
__device__ __forceinline__ float bf2f(unsigned short b) {
  return __uint_as_float(((unsigned)b) << 16);
}

#define GLD16(gptr, lptr)                                                     \
  __builtin_amdgcn_global_load_lds(                                           \
      (const __attribute__((address_space(1))) void*)(gptr),                  \
      (__attribute__((address_space(3))) void*)(lptr), 16, 0, 0)

__device__ __forceinline__ int wave_incl_scan(int v, int lane) {
#pragma unroll
  for (int off = 1; off < 64; off <<= 1) {
    int t = __shfl_up(v, off);
    if (lane >= off) v += t;
  }
  return v;
}

// ---------------- compaction scan (single block) ----------------
__global__ __launch_bounds__(1024) void scan_kernel(
    const int* __restrict__ mask, const int* __restrict__ rptr,
    int* __restrict__ ru, int* __restrict__ unm_idx,
    int* __restrict__ msk_idx, int* __restrict__ pos2row,
    int* __restrict__ counts) {
  __shared__ int sru[4097];
  __shared__ int wsum[16];
  __shared__ int wsum2[17];
  const int tid = threadIdx.x;
  const int lane = tid & 63, wv = tid >> 6;
  const int t0 = tid * 4;
  const int4 m4 = *(const int4*)(mask + t0);
  int f[4];
  f[0] = (m4.x == 0); f[1] = (m4.y == 0); f[2] = (m4.z == 0); f[3] = (m4.w == 0);
  const int tsum = f[0] + f[1] + f[2] + f[3];
  const int isc = wave_incl_scan(tsum, lane);
  if (lane == 63) wsum[wv] = isc;
  __syncthreads();
  if (tid == 0) {
    int acc = 0;
#pragma unroll
    for (int i = 0; i < 16; ++i) { int v = wsum[i]; wsum[i] = acc; acc += v; }
    sru[4096] = acc;
    counts[0] = acc;
    ru[4096] = acc;
  }
  __syncthreads();
  int ex = wsum[wv] + isc - tsum;
#pragma unroll
  for (int j = 0; j < 4; ++j) {
    sru[t0 + j] = ex;
    ru[t0 + j] = ex;
    if (f[j]) unm_idx[ex] = t0 + j;
    ex += f[j];
  }
  __syncthreads();
  // pass 2: masked positions with >=1 valid neighbor
  const int r = rptr[0];
  int mval[4] = {m4.x, m4.y, m4.z, m4.w};
  int g[4];
#pragma unroll
  for (int j = 0; j < 4; ++j) {
    const int t = t0 + j;
    const int s = t & 2047, tb = t & ~2047;
    const int lo = max(s - r, 0), hi = min(s + r, 2047);
    const int cnt = sru[tb + hi + 1] - sru[tb + lo];
    g[j] = (mval[j] != 0 && cnt > 0) ? 1 : 0;
  }
  const int tsum2 = g[0] + g[1] + g[2] + g[3];
  const int isc2 = wave_incl_scan(tsum2, lane);
  if (lane == 63) wsum2[wv] = isc2;
  __syncthreads();
  if (tid == 0) {
    int acc = 0;
#pragma unroll
    for (int i = 0; i < 16; ++i) { int v = wsum2[i]; wsum2[i] = acc; acc += v; }
    counts[1] = acc;
  }
  __syncthreads();
  int ex2 = wsum2[wv] + isc2 - tsum2;
#pragma unroll
  for (int j = 0; j < 4; ++j) {
    const int t = t0 + j;
    pos2row[t] = g[j] ? ex2 : -1;
    if (g[j]) msk_idx[ex2] = t;
    ex2 += g[j];
  }
}

// ---------------- fused: router softmax + bf16 pack of unmasked h rows ----
__global__ void packrouter_kernel(const float* __restrict__ h,
                                  const int* __restrict__ mask,
                                  const int* __restrict__ ru,
                                  const float* __restrict__ Wr,
                                  const float* __restrict__ br,
                                  float* __restrict__ w,
                                  unsigned short* __restrict__ hbc) {
  const int a = blockIdx.x;
  const int tid = threadIdx.x;
  const int lane = tid & 63, wid = tid >> 6;
  const size_t base = (size_t)a * 2048;
  const int d0 = tid * 8;
  float hv[8];
  *(float4*)(hv) = *(const float4*)(h + base + d0);
  *(float4*)(hv + 4) = *(const float4*)(h + base + d0 + 4);
  float acc[8];
#pragma unroll
  for (int k = 0; k < 8; ++k) {
    float wvv[8];
    *(float4*)(wvv) = *(const float4*)(Wr + (size_t)k * 2048 + d0);
    *(float4*)(wvv + 4) = *(const float4*)(Wr + (size_t)k * 2048 + d0 + 4);
    float s = 0.f;
#pragma unroll
    for (int j = 0; j < 8; ++j) s += hv[j] * wvv[j];
    acc[k] = s;
  }
#pragma unroll
  for (int off = 32; off > 0; off >>= 1)
#pragma unroll
    for (int k = 0; k < 8; ++k) acc[k] += __shfl_down(acc[k], off);
  __shared__ float red[4][8];
  __shared__ float logits[8];
  if (lane == 0)
#pragma unroll
    for (int k = 0; k < 8; ++k) red[wid][k] = acc[k];
  __syncthreads();
  if (tid < 8)
    logits[tid] = red[0][tid] + red[1][tid] + red[2][tid] + red[3][tid] + br[tid];
  __syncthreads();
  if (tid == 0) {
    float mx = logits[0];
#pragma unroll
    for (int k = 1; k < 8; ++k) mx = fmaxf(mx, logits[k]);
    float e[8], se = 0.f;
#pragma unroll
    for (int k = 0; k < 8; ++k) {
      e[k] = expf(logits[k] - mx);
      se += e[k];
    }
    const float is = 1.f / se;
#pragma unroll
    for (int k = 0; k < 8; ++k) w[(size_t)a * 8 + k] = e[k] * is;
  }
  if (mask[a] == 0) {
    const int i = ru[a];
    short8 o;
#pragma unroll
    for (int j = 0; j < 8; ++j) o[j] = (short)f2bf(hv[j]);
    *(short8*)(hbc + (size_t)i * 2048 + d0) = o;
  }
}

// ---------------- transpose-pack weights (f32 [R][C] -> bf16 dst[c*stride + r]) ----------------
__global__ void transpose_pack_kernel(const float* __restrict__ src,
                                      unsigned short* __restrict__ dst,
                                      int R, int C, size_t dstStride,
                                      size_t dstExpStride) {
  __shared__ float tile[32][33];
  const int k = blockIdx.z;
  src += (size_t)k * (size_t)R * (size_t)C;
  dst += (size_t)k * dstExpStride;
  const int c0 = blockIdx.x * 32;
  const int r0 = blockIdx.y * 32;
  const int tx = threadIdx.x;  // 0..31
  const int ty = threadIdx.y;  // 0..7
#pragma unroll
  for (int i = 0; i < 4; ++i)
    tile[ty + 8 * i][tx] = src[(size_t)(r0 + ty + 8 * i) * C + (c0 + tx)];
  __syncthreads();
#pragma unroll
  for (int i = 0; i < 4; ++i) {
    const int c = c0 + ty + 8 * i;
    dst[(size_t)c * dstStride + (size_t)(r0 + tx)] = f2bf(tile[tx][ty + 8 * i]);
  }
}

// ---------------- GEMM C = A * Bt^T (A [M][Kd], Bt [N][Kd], both bf16 row-major) ----------------
// 128x128 tile, BK=32, 4 waves (2x2), 16x16x32 MFMA, global_load_lds width 16.
// 4-buffer depth-3 prefetch, counted vmcnt (T3/T4): loads stay in flight
// across barriers; one raw s_barrier per K-step; vmcnt(8) steady state.
// M limited at runtime by counts[cidx]; blocks fully past the limit exit.
template <int EPI>  // 0: store f32 C. 1: +bias, exact GELU, store bf16.
__global__ __launch_bounds__(256, 2) void gemm_bt_kernel(
    const unsigned short* __restrict__ A, const unsigned short* __restrict__ Bt,
    float* __restrict__ Cf, unsigned short* __restrict__ Cb,
    const float* __restrict__ bias, const int* __restrict__ counts, int cidx,
    int N, int Kd) {
  const int Mlim = counts[cidx];
  const int bm = blockIdx.y * 128;
  if (bm >= Mlim) return;
  // L[buf][0..4095] = A-tile (128 rows x 32 k), L[buf][4096..8191] = B-tile
  __shared__ __align__(16) unsigned short L[4][8192];
  const int tid = threadIdx.x;
  const int lane = tid & 63;
  const int wid = tid >> 6;
  const int bn = blockIdx.x * 128;
  const int wr = wid >> 1;
  const int wc = wid & 1;

  f32x4 acc[4][4];
#pragma unroll
  for (int m = 0; m < 4; ++m)
#pragma unroll
    for (int n = 0; n < 4; ++n) acc[m][n] = (f32x4){0.f, 0.f, 0.f, 0.f};

  const int srow = wid * 16 + (lane >> 2);
  const int scol = (lane & 3) * 8;
  const unsigned short* gA0 = A + (size_t)(bm + srow) * Kd + scol;
  const unsigned short* gA1 = gA0 + (size_t)64 * Kd;
  const unsigned short* gB0 = Bt + (size_t)(bn + srow) * Kd + scol;
  const unsigned short* gB1 = gB0 + (size_t)64 * Kd;

  const int aoff = (wr * 64 + (lane & 15)) * 32 + (lane >> 4) * 8;
  const int boff = (wc * 64 + (lane & 15)) * 32 + (lane >> 4) * 8;

#define STAGE(buf, t)                                                         \
  {                                                                           \
    const int k0_ = (t) << 5;                                                 \
    unsigned short* la_ = &L[(buf)][0] + wid * 512;                           \
    unsigned short* lb_ = &L[(buf)][4096] + wid * 512;                        \
    GLD16(gA0 + k0_, la_);                                                    \
    GLD16(gA1 + k0_, la_ + 2048);                                             \
    GLD16(gB0 + k0_, lb_);                                                    \
    GLD16(gB1 + k0_, lb_ + 2048);                                             \
  }

#define COMPUTE(buf)                                                          \
  {                                                                           \
    const unsigned short* As_ = &L[(buf)][0];                                 \
    const unsigned short* Bs_ = &L[(buf)][4096];                              \
    bf16x8 af[4], bfr[4];                                                     \
    _Pragma("unroll") for (int m = 0; m < 4; ++m) af[m] =                     \
        __builtin_bit_cast(bf16x8, *(const short8*)(As_ + aoff + m * 512));   \
    _Pragma("unroll") for (int n = 0; n < 4; ++n) bfr[n] =                    \
        __builtin_bit_cast(bf16x8, *(const short8*)(Bs_ + boff + n * 512));   \
    _Pragma("unroll") for (int m = 0; m < 4; ++m)                             \
        _Pragma("unroll") for (int n = 0; n < 4; ++n) acc[m][n] =             \
            __builtin_amdgcn_mfma_f32_16x16x32_bf16(af[m], bfr[n],            \
                                                    acc[m][n], 0, 0, 0);      \
  }

  const int nt = Kd >> 5;  // 64 or 128, always >= 4
  STAGE(0, 0);
  STAGE(1, 1);
  STAGE(2, 2);
#pragma unroll 1
  for (int t = 0; t < nt - 3; ++t) {
    asm volatile("s_waitcnt vmcnt(8)" ::: "memory");  // tile t landed (mine)
    __builtin_amdgcn_s_barrier();                     // everyone's tile t landed;
    __builtin_amdgcn_sched_barrier(0);                // tile t-1 reads all done
    STAGE((t + 3) & 3, t + 3);  // overwrites tile t-1's buffer: safe post-barrier
    COMPUTE(t & 3);
  }
  {
    asm volatile("s_waitcnt vmcnt(8)" ::: "memory");
    __builtin_amdgcn_s_barrier();
    __builtin_amdgcn_sched_barrier(0);
    COMPUTE((nt - 3) & 3);
  }
  {
    asm volatile("s_waitcnt vmcnt(4)" ::: "memory");
    __builtin_amdgcn_s_barrier();
    __builtin_amdgcn_sched_barrier(0);
    COMPUTE((nt - 2) & 3);
  }
  {
    asm volatile("s_waitcnt vmcnt(0)" ::: "memory");
    __builtin_amdgcn_s_barrier();
    __builtin_amdgcn_sched_barrier(0);
    COMPUTE((nt - 1) & 3);
  }
#undef STAGE
#undef COMPUTE

  // C/D layout: col = lane&15, row = (lane>>4)*4 + i (m89/m91-verified)
  const int r0 = bm + wr * 64 + (lane >> 4) * 4;
  const int c0 = bn + wc * 64 + (lane & 15);
#pragma unroll
  for (int m = 0; m < 4; ++m) {
#pragma unroll
    for (int n = 0; n < 4; ++n) {
      const int col = c0 + n * 16;
#pragma unroll
      for (int i = 0; i < 4; ++i) {
        const int row = r0 + m * 16 + i;
        if (row >= Mlim) continue;
        const size_t off = (size_t)row * N + col;
        float v = acc[m][n][i];
        if (EPI == 1) {
          v += bias[col];
          v = 0.5f * v * (1.0f + erff(v * 0.70710678118654752f));  // exact GELU
          Cb[off] = f2bf(v);
        } else {
          Cf[off] = v;
        }
      }
    }
  }
}

// ---------------- windowed neighbor sum + router weighting (compact) -------
__global__ void window_kernel(const unsigned short* __restrict__ Act_c,
                              const float* __restrict__ w,
                              const int* __restrict__ msk_idx,
                              const int* __restrict__ ru,
                              const int* __restrict__ rptr,
                              const int* __restrict__ counts,
                              unsigned short* __restrict__ G_c) {
  const int i = blockIdx.y;
  if (i >= counts[1]) return;
  const int a = msk_idx[i];
  const int s = a & 2047;
  const int tb = a & ~2047;
  const int r = rptr[0];
  const int lo = max(s - r, 0), hi = min(s + r, 2047);
  const int jlo = ru[tb + lo], jhi = ru[tb + hi + 1];
  const int c = blockIdx.x * 2048 + threadIdx.x * 8;
  float acc[8] = {0.f, 0.f, 0.f, 0.f, 0.f, 0.f, 0.f, 0.f};
  for (int j = jlo; j < jhi; ++j) {
    const short8 v = *(const short8*)(Act_c + (size_t)j * 4096 + c);
#pragma unroll
    for (int jj = 0; jj < 8; ++jj) acc[jj] += bf2f((unsigned short)v[jj]);
  }
  const float wv = w[(size_t)a * 8 + (c >> 9)];
  short8 o8;
#pragma unroll
  for (int jj = 0; jj < 8; ++jj) o8[jj] = (short)f2bf(acc[jj] * wv);
  *(short8*)(G_c + (size_t)i * 4096 + c) = o8;
}

// ---------------- final: bias-combine, mean, LN, blend ----------------
__global__ void final_kernel(const float* __restrict__ h,
                             const int* __restrict__ pos2row,
                             const float* __restrict__ w,
                             const float* __restrict__ b2,
                             const float* __restrict__ num_c,
                             const int* __restrict__ ru,
                             const int* __restrict__ rptr,
                             float* __restrict__ out) {
  const int a = blockIdx.x;
  const int tid = threadIdx.x;
  const int lane = tid & 63, wid = tid >> 6;
  const size_t base = (size_t)a * 2048;
  const int d0 = tid * 8;
  const int row = pos2row[a];
  if (row < 0) {  // block-uniform: exact fp32 pass-through
    const float4 x0 = *(const float4*)(h + base + d0);
    const float4 x1 = *(const float4*)(h + base + d0 + 4);
    *(float4*)(out + base + d0) = x0;
    *(float4*)(out + base + d0 + 4) = x1;
    return;
  }
  const int s = a & 2047;
  const int tb = a & ~2047;
  const int r = rptr[0];
  const int lo = max(s - r, 0), hi = min(s + r, 2047);
  const int cnt = ru[tb + hi + 1] - ru[tb + lo];
  float wk[8];
#pragma unroll
  for (int k = 0; k < 8; ++k) wk[k] = w[(size_t)a * 8 + k];
  const float cntf = (float)cnt;
  const float icnt = 1.0f / cntf;
  float mval[8];
  float s1 = 0.f, s2 = 0.f;
#pragma unroll
  for (int j = 0; j < 8; ++j) {
    const int d = d0 + j;
    float wb2 = 0.f;
#pragma unroll
    for (int k = 0; k < 8; ++k) wb2 += wk[k] * b2[(size_t)k * 2048 + d];
    const float v = (num_c[(size_t)row * 2048 + d] + cntf * wb2) * icnt;
    mval[j] = v;
    s1 += v;
    s2 += v * v;
  }
#pragma unroll
  for (int off = 32; off > 0; off >>= 1) {
    s1 += __shfl_down(s1, off);
    s2 += __shfl_down(s2, off);
  }
  __shared__ float red[8];
  if (lane == 0) {
    red[wid] = s1;
    red[4 + wid] = s2;
  }
  __syncthreads();
  const float S1 = red[0] + red[1] + red[2] + red[3];
  const float S2 = red[4] + red[5] + red[6] + red[7];
  const float mu = S1 * (1.0f / 2048.0f);
  const float var = S2 * (1.0f / 2048.0f) - mu * mu;
  const float rin = rsqrtf(var + EPS);
#pragma unroll
  for (int j = 0; j < 8; ++j) {
    const int d = d0 + j;
    out[base + d] = h[base + d] + ALPHA * ((mval[j] - mu) * rin);
  }
}

// ---------------- launch ----------------
extern "C" void kernel_launch(void* const* d_in, const int* in_sizes, int n_in,
                              void* d_out, int out_size, void* d_ws,
                              size_t ws_size, hipStream_t stream) {
  const float* h = (const float*)d_in[0];
  const int* mask = (const int*)d_in[1];
  const float* Wr = (const float*)d_in[2];
  const float* br = (const float*)d_in[3];
  const float* W1 = (const float*)d_in[4];
  const float* b1 = (const float*)d_in[5];
  const float* W2 = (const float*)d_in[6];
  const float* b2 = (const float*)d_in[7];
  const int* rptr = (const int*)d_in[8];
  float* out = (float*)d_out;

  char* ws = (char*)d_ws;
  // layout (bytes):
  //   hbc  [4096*2048] bf16 @ 0          (16 MiB)  compact unmasked h, bf16
  //   B1t  [4096*2048] bf16 @ 16777216   (16 MiB)  W1^T stacked: [kf][d]
  //   B2t  [2048*4096] bf16 @ 33554432   (16 MiB)  W2^T stacked: [d][kf]
  //   Act_c[4096*4096] bf16 @ 50331648   (32 MiB)  (aliased by num_c f32 later)
  //   G_c  [4096*4096] bf16 @ 83886080   (32 MiB)
  //   w    [4096*8]    f32  @ 117440512  (128 KiB)
  //   ints: ru[4097+], unm_idx[4096], msk_idx[4096], pos2row[4096], counts[2]
  unsigned short* hbc = (unsigned short*)(ws + 0);
  unsigned short* B1t = (unsigned short*)(ws + 16777216);
  unsigned short* B2t = (unsigned short*)(ws + 33554432);
  unsigned short* Act_c = (unsigned short*)(ws + 50331648);
  unsigned short* G_c = (unsigned short*)(ws + 83886080);
  float* num_c = (float*)(ws + 50331648);  // alias Act_c (dead after window)
  float* wbuf = (float*)(ws + 117440512);
  int* ru = (int*)(ws + 117571584);
  int* unm_idx = ru + 4100;
  int* msk_idx = unm_idx + 4096;
  int* pos2row = msk_idx + 4096;
  int* counts = pos2row + 4096;

  scan_kernel<<<1, 1024, 0, stream>>>(mask, rptr, ru, unm_idx, msk_idx,
                                      pos2row, counts);
  packrouter_kernel<<<4096, 256, 0, stream>>>(h, mask, ru, Wr, br, wbuf, hbc);
  // W1 [k][d][f] -> B1t[(k*512+f)*2048 + d]
  transpose_pack_kernel<<<dim3(16, 64, 8), dim3(32, 8), 0, stream>>>(
      W1, B1t, 2048, 512, 2048, (size_t)512 * 2048);
  // W2 [k][f][d] -> B2t[d*4096 + k*512 + f]
  transpose_pack_kernel<<<dim3(64, 16, 8), dim3(32, 8), 0, stream>>>(
      W2, B2t, 512, 2048, 4096, 512);
  // GEMM1: Act_c = gelu(hbc * B1t^T + b1)   [Nu x 4096], Kd=2048
  gemm_bt_kernel<1><<<dim3(32, 32), 256, 0, stream>>>(
      hbc, B1t, nullptr, Act_c, b1, counts, 0, 4096, 2048);
  // G_c = w * windowed-sum(Act_c)   [Nm x 4096]
  window_kernel<<<dim3(2, 4096), 256, 0, stream>>>(Act_c, wbuf, msk_idx, ru,
                                                   rptr, counts, G_c);
  // GEMM2: num_c = G_c * B2t^T   [Nm x 2048], Kd=4096
  gemm_bt_kernel<0><<<dim3(16, 32), 256, 0, stream>>>(
      G_c, B2t, num_c, nullptr, nullptr, counts, 1, 2048, 4096);
  final_kernel<<<4096, 256, 0, stream>>>(h, pos2row, wbuf, b2, num_c, ru,
                                         rptr, out);
}